// Round 4
// baseline (1078.971 us; speedup 1.0000x reference)
//
#include <hip/hip_runtime.h>
#include <math.h>

// Problem constants (fixed by the reference): B=256, S=2048, I=32, H=128, O=1
#define B_ 256
#define S_ 2048
#define I_ 32
#define H_ 128

// Barrier WITHOUT vmcnt(0) drain (HIP __syncthreads waits vmcnt(0) before
// s_barrier, stalling on in-flight global prefetch/stores every step).
// LDS visibility only needs lgkmcnt(0).
__device__ __forceinline__ void sync_lds() {
    asm volatile("" ::: "memory");
    asm volatile("s_waitcnt lgkmcnt(0)" ::: "memory");
    __builtin_amdgcn_s_barrier();
    asm volatile("" ::: "memory");
}

// tanh(z) = 1 - 2/(e^{2z}+1); exact limits at +-inf, abs err ~1e-7.
__device__ __forceinline__ float fast_tanh(float z) {
    float e = __expf(2.0f * z);
    return 1.0f - 2.0f / (e + 1.0f);
}

template <int CTRL>
__device__ __forceinline__ float dppf(float v) {
    return __int_as_float(__builtin_amdgcn_update_dpp(
        0, __float_as_int(v), CTRL, 0xF, 0xF, false));
}
// DPP controls: 0xB1 = quad_perm [1,0,3,2] (xor1), 0x4E = quad_perm [2,3,0,1]
// (xor2), 0x141 = row_half_mirror (l^7; == xor4 once b0,b1 are reduced),
// 0x128 = row_ror:8 (pure xor8 within a 16-lane row).

// LDS-pipe lane exchanges (full-wave): xor16 via ds_swizzle BitMode,
// xor32 via ds_bpermute (crossbar, no LDS storage touched). Both proven
// on this HW (rounds 3: absmax 0.0).
__device__ __forceinline__ float swz_xor16(float v) {
    return __int_as_float(__builtin_amdgcn_ds_swizzle(__float_as_int(v), 0x401F));
}
__device__ __forceinline__ float bperm_f(int addr_bytes, float v) {
    return __int_as_float(__builtin_amdgcn_ds_bpermute(addr_bytes, __float_as_int(v)));
}

// a0..a3 += hval * WhR4[idx].{x,y,z,w}  (4 h per lane)
#define MACC(hval, idx)                              \
    a0 = fmaf(hval, WhR4[(idx)].x, a0);              \
    a1 = fmaf(hval, WhR4[(idx)].y, a1);              \
    a2 = fmaf(hval, WhR4[(idx)].z, a2);              \
    a3 = fmaf(hval, WhR4[(idx)].w, a3);
#define MACQ(hv, q)                                  \
    MACC((hv).x, 4 * (q) + 0)                        \
    MACC((hv).y, 4 * (q) + 1)                        \
    MACC((hv).z, 4 * (q) + 2)                        \
    MACC((hv).w, 4 * (q) + 3)

// One step, s = g*8 + PH (PH compile-time -> ring indices fold).
// 4 waves per batch (1 wave/SIMD), wave w owns h in [32w, 32w+32).
// Lane: 4 h x 16 k (64 FMA). Lane bits: k = {b0,b1,b3} (kg3, 8 groups x 16 k),
// h-group = {b2,b4,b5} (hg, 8 groups x 4 h), role j = b0+2*b1 selects the
// lane's final h during the reduction.
// k-tree (pure DPP, no LDS): xor1 role-split (4 acc -> 2), xor2 role-split
// (2 -> 1), ror:8 (b3). Result: hn for hfin = 32w+4hg+(l&3), 2 copies (b3).
// x.Wi is folded into the accumulator init (4 i per lane over the same
// k-bits), so it shares the k-tree. Bias added post-reduction (exact, 1/h).
// Score/proj (DEFERRED 1 step): b3 = class bit (pv vs qv; each h enters each
// class exactly once -> no scale). Reduce over {b0,b1,b2,b4,b5}: xor1, xor2
// (DPP), row_half_mirror (==xor4 after b0,b1 uniform), swizzle xor16,
// bpermute xor32. Lanes 0/8 write {pv,qv} to pl_lds ring; wave 0 combines
// the 4 wave-partials of step s-2 (2-level DPP tree) and stores part[].
#define STEP_BODY(g, PH, XS, CPH)                                             \
  {                                                                           \
    const int s_ = (g) * 8 + (PH);                                            \
    const float4* hsrc = (const float4*)&h0_lds[(PH) & 1][0];                 \
    float4 hv0 = hsrc[kg3];                                                   \
    float4 hv1 = hsrc[kg3 + 8];                                               \
    float4 hv2 = hsrc[kg3 + 16];                                              \
    float4 hv3 = hsrc[kg3 + 24];                                              \
    if (s_ >= 1) {   /* deferred score/proj reduce of step s-1 */             \
      float r = uP;                                                           \
      r += dppf<0xB1>(r);                                                     \
      r += dppf<0x4E>(r);                                                     \
      r += dppf<0x141>(r);                                                    \
      r += swz_xor16(r);                                                      \
      r += bperm_f(bp32, r);                                                  \
      if ((l & 0x37) == 0)                                                    \
        ((float*)&pl_lds[(unsigned)(s_ - 1) & 3][w])[(l >> 3) & 1] = r;       \
    }                                                                         \
    if (w == 0 && s_ >= 2) {  /* combine partials of step s-2 */              \
      float2 pp = pl_lds[(unsigned)(s_ - 2) & 3][l & 3];                      \
      float px = pp.x, py = pp.y;                                             \
      px += dppf<0xB1>(px);  py += dppf<0xB1>(py);                            \
      px += dppf<0x4E>(px);  py += dppf<0x4E>(py);                            \
      if (l == 0) part[((s_ - 2) << 8) + b] = make_float2(px, py);            \
    }                                                                         \
    float a0 = (XS).x * WiC4[0].x;                                            \
    float a1 = (XS).x * WiC4[0].y;                                            \
    float a2 = (XS).x * WiC4[0].z;                                            \
    float a3 = (XS).x * WiC4[0].w;                                            \
    a0 = fmaf((XS).y, WiC4[1].x, a0); a1 = fmaf((XS).y, WiC4[1].y, a1);       \
    a2 = fmaf((XS).y, WiC4[1].z, a2); a3 = fmaf((XS).y, WiC4[1].w, a3);       \
    a0 = fmaf((XS).z, WiC4[2].x, a0); a1 = fmaf((XS).z, WiC4[2].y, a1);       \
    a2 = fmaf((XS).z, WiC4[2].z, a2); a3 = fmaf((XS).z, WiC4[2].w, a3);       \
    a0 = fmaf((XS).w, WiC4[3].x, a0); a1 = fmaf((XS).w, WiC4[3].y, a1);       \
    a2 = fmaf((XS).w, WiC4[3].z, a2); a3 = fmaf((XS).w, WiC4[3].w, a3);       \
    MACQ(hv0, 0) MACQ(hv1, 1) MACQ(hv2, 2) MACQ(hv3, 3)                       \
    float s0 = a0 + dppf<0xB1>(a0);                                           \
    float s1 = a1 + dppf<0xB1>(a1);                                           \
    float s2 = a2 + dppf<0xB1>(a2);                                           \
    float s3 = a3 + dppf<0xB1>(a3);                                           \
    float u0 = kb0 ? s1 : s0;                                                 \
    float u1 = kb0 ? s3 : s2;                                                 \
    u0 += dppf<0x4E>(u0);                                                     \
    u1 += dppf<0x4E>(u1);                                                     \
    float tt = kb1 ? u1 : u0;                                                 \
    tt += dppf<0x128>(tt);                                                    \
    float hn = tt + biasR;                                                    \
    if (s_ < S_ - 2) {  /* refill slot with x row s+2 (imm offset) */         \
      (XS) = *(const float4*)(xgrp + ((PH) + 2) * I_);                        \
    }                                                                         \
    uP = hn * (CPH);                /* reduced at top of next step */         \
    float h0n;                                                                \
    if (s_ == 0)            { hstartR = hn; h0n = 0.0f; }                     \
    else if (s_ == S_ - 2)  { h0n = fast_tanh(hn + hstartR); }                \
    else if (rd == 1)       { h0n = fast_tanh(hn + h0R); }                    \
    else if (cnt == 0)      { h0n = fast_tanh(hn + htR); htR = hn; }          \
    else                    { h0n = fast_tanh(hn); }                          \
    h0R = h0n;                                                                \
    if (wmask) h0_lds[((PH) + 1) & 1][hf] = h0n;                              \
    cnt = (cnt + 1 == rd) ? 0 : cnt + 1;                                      \
    sync_lds();                                                               \
  }

// 256 threads = 4 waves per batch (1 wave/SIMD), 1 batch/block, 256 blocks.
// Model (rounds 0-3, measured): wall = per-SIMD VALU issue (1:1 verified by
// the r2->r3 delta) + fixed C ~ 850 cy = barrier-width/skew + post-barrier
// ds_read latency + serial chain. This round halves barrier participants
// and the LDS read burst (16 vs 32 ds_read_b128/CU), makes the k-tree pure
// DPP, and drops per-step overhead waves. waves_per_eu(1,1): allocator
// unconstrained (static demand ~130 VGPR, 1 wave/SIMD is the design point).
__global__ __launch_bounds__(256)
__attribute__((amdgpu_waves_per_eu(1, 1)))
void rnn_kernel(
    const float* __restrict__ x, const float* __restrict__ Wi,
    const float* __restrict__ bi, const float* __restrict__ Wh,
    const float* __restrict__ bh, const float* __restrict__ Wa,
    const float* __restrict__ Wd, const int* __restrict__ rdp,
    float2* __restrict__ part)
{
    const int b = blockIdx.x;
    const int t = threadIdx.x;
    const int w = t >> 6;           // wave id 0..3
    const int l = t & 63;
    // k-bits {0,1,3} -> kg3; h-group bits {2,4,5} -> hg; role j = l&3
    const int  kg3   = (l & 3) | (((l >> 3) & 1) << 2);              // 0..7
    const int  hg    = ((l >> 2) & 1) | (((l >> 4) & 1) << 1)
                     | (((l >> 5) & 1) << 2);                        // 0..7
    const int  hbase4 = 32 * w + 4 * hg;
    const int  hf     = hbase4 + (l & 3);   // this lane's final h
    const bool kb0    = (l & 1);
    const bool kb1    = (l >> 1) & 1;
    const bool wmask  = ((l & 8) == 0);     // 32 writer lanes (distinct h)
    const int  i0x    = 4 * kg3;            // 0,4,...,28
    const int  bp32   = (l ^ 32) << 2;      // bpermute byte addr for xor32

    __shared__ __align__(16) float h0_lds[2][H_];
    __shared__ __align__(8)  float2 pl_lds[4][4];   // 4-deep ring x 4 waves

    const int rd = rdp[0];
    if (t < H_) h0_lds[0][t] = 0.0f;

    // Wh: lane's 16 k (k = 4*(kg3+8q)+c) x 4 h (hbase4..hbase4+4)
    float4 WhR4[16];
#pragma unroll
    for (int q = 0; q < 4; ++q)
#pragma unroll
        for (int c = 0; c < 4; ++c) {
            int k = 4 * (kg3 + 8 * q) + c;
            WhR4[q * 4 + c] = *(const float4*)(Wh + (size_t)k * H_ + hbase4);
        }
    // Wi: lane's 4 i x 4 h
    float4 WiC4[4];
#pragma unroll
    for (int i = 0; i < 4; ++i)
        WiC4[i] = *(const float4*)(Wi + (size_t)(i0x + i) * H_ + hbase4);
    const float biasR = bi[hf] + bh[hf];    // post-reduction, exact once per h

    // Per-phase score/proj coefficient: class bit b3 selects pv (Wa) or qv
    // (Wd column for this b, phase s&7). Class-preserving reduce -> each h
    // counted exactly once per class, no duplication scale.
    const bool clsq = (l >> 3) & 1;
    const float waC = Wa[hf];
    float cph[8];
#pragma unroll
    for (int K = 0; K < 8; ++K)
        cph[K] = clsq ? Wd[(K << 15) + (b << 7) + hf] : waC;

    // x group pointer: rows of this group reachable via imm offsets
    const float* xgrp = x + (size_t)b * (S_ * I_) + i0x;
    float4 xS0 = *(const float4*)xgrp;          // even-s slot
    float4 xS1 = *(const float4*)(xgrp + I_);   // odd-s slot

    sync_lds();

    float htR = 0.f, hstartR = 0.f, h0R = 0.f;
    float uP = 0.f;   // previous step's (hn * coef), reduced next step
    int cnt = 0;      // s % rd, incremental

    for (int g = 0; g < S_ / 8; ++g) {
        STEP_BODY(g, 0, xS0, cph[0])
        STEP_BODY(g, 1, xS1, cph[1])
        STEP_BODY(g, 2, xS0, cph[2])
        STEP_BODY(g, 3, xS1, cph[3])
        STEP_BODY(g, 4, xS0, cph[4])
        STEP_BODY(g, 5, xS1, cph[5])
        STEP_BODY(g, 6, xS0, cph[6])
        STEP_BODY(g, 7, xS1, cph[7])
        xgrp += 8 * I_;
    }

    // epilogue: reduce s = S-1's partial into ring 3, then wave 0 combines
    // rings 2 (s = S-2, written at top of step S-1) and 3.
    {
        float r = uP;
        r += dppf<0xB1>(r);
        r += dppf<0x4E>(r);
        r += dppf<0x141>(r);
        r += swz_xor16(r);
        r += bperm_f(bp32, r);
        if ((l & 0x37) == 0)
            ((float*)&pl_lds[3][w])[(l >> 3) & 1] = r;
    }
    sync_lds();
    if (w == 0) {
#pragma unroll
        for (int e = 0; e < 2; ++e) {
            float2 pp = pl_lds[2 + e][l & 3];
            float px = pp.x, py = pp.y;
            px += dppf<0xB1>(px);  py += dppf<0xB1>(py);
            px += dppf<0x4E>(px);  py += dppf<0x4E>(py);
            if (l == 0) part[((S_ - 2 + e) << 8) + b] = make_float2(px, py);
        }
    }
}

// out[r] = bd + sum_{f in chunk r} softmax(score)_f * d_f, chunk = 2048 flat
// (s,b) pairs with s in [8r,8r+8). ba is softmax-invariant -> omitted.
__global__ __launch_bounds__(256) void attn_kernel(
    const float2* __restrict__ part, const float* __restrict__ bd,
    float* __restrict__ out)
{
    const int r = blockIdx.x;
    const int t = threadIdx.x;
    float sc[8], dv[8];
    float mx = -1e30f;
#pragma unroll
    for (int u = 0; u < 8; ++u) {
        int f = (r << 11) + (u << 8) + t;
        float2 a = part[f];
        sc[u] = a.x;
        dv[u] = a.y;
        mx = fmaxf(mx, sc[u]);
    }
    __shared__ float redm[4], redz[4], redw[4];
#pragma unroll
    for (int off = 32; off > 0; off >>= 1) mx = fmaxf(mx, __shfl_xor(mx, off, 64));
    if ((t & 63) == 0) redm[t >> 6] = mx;
    __syncthreads();
    mx = fmaxf(fmaxf(redm[0], redm[1]), fmaxf(redm[2], redm[3]));
    float z = 0.f, wv = 0.f;
#pragma unroll
    for (int u = 0; u < 8; ++u) {
        float e = __expf(sc[u] - mx);
        z += e;
        wv += e * dv[u];
    }
#pragma unroll
    for (int off = 32; off > 0; off >>= 1) {
        z += __shfl_xor(z, off, 64);
        wv += __shfl_xor(wv, off, 64);
    }
    if ((t & 63) == 0) { redz[t >> 6] = z; redw[t >> 6] = wv; }
    __syncthreads();
    if (t == 0) {
        float Z = redz[0] + redz[1] + redz[2] + redz[3];
        float W = redw[0] + redw[1] + redw[2] + redw[3];
        out[r] = bd[0] + W / Z;
    }
}

extern "C" void kernel_launch(void* const* d_in, const int* in_sizes, int n_in,
                              void* d_out, int out_size, void* d_ws, size_t ws_size,
                              hipStream_t stream) {
    const float* x  = (const float*)d_in[0];
    const float* Wi = (const float*)d_in[1];
    const float* bi = (const float*)d_in[2];
    const float* Wh = (const float*)d_in[3];
    const float* bh = (const float*)d_in[4];
    const float* Wa = (const float*)d_in[5];
    // d_in[6] = ba: constant shift inside each softmax chunk -> no effect.
    const float* Wd = (const float*)d_in[7];
    const float* bd = (const float*)d_in[8];
    const int*  rdp = (const int*)d_in[9];

    // Workspace: one (S*B) float2 array of combined {score, d} (4 MiB)
    float2* part = (float2*)d_ws;

    rnn_kernel<<<B_, 256, 0, stream>>>(x, Wi, bi, Wh, bh, Wa, Wd, rdp, part);
    attn_kernel<<<B_, 256, 0, stream>>>(part, bd, (float*)d_out);
}

// Round 5
// 929.407 us; speedup vs baseline: 1.1609x; 1.1609x over previous
//
#include <hip/hip_runtime.h>
#include <math.h>

// Problem constants (fixed by the reference): B=256, S=2048, I=32, H=128, O=1
#define B_ 256
#define S_ 2048
#define I_ 32
#define H_ 128

// Barrier WITHOUT vmcnt(0) drain (HIP __syncthreads waits vmcnt(0) before
// s_barrier, stalling on in-flight global prefetch/stores every step).
// LDS visibility only needs lgkmcnt(0).
__device__ __forceinline__ void sync_lds() {
    asm volatile("" ::: "memory");
    asm volatile("s_waitcnt lgkmcnt(0)" ::: "memory");
    __builtin_amdgcn_s_barrier();
    asm volatile("" ::: "memory");
}

// tanh(z) = 1 - 2/(e^{2z}+1); exact limits at +-inf, abs err ~1e-7.
__device__ __forceinline__ float fast_tanh(float z) {
    float e = __expf(2.0f * z);
    return 1.0f - 2.0f / (e + 1.0f);
}

template <int CTRL>
__device__ __forceinline__ float dppf(float v) {
    return __int_as_float(__builtin_amdgcn_update_dpp(
        0, __float_as_int(v), CTRL, 0xF, 0xF, false));
}
// DPP controls: 0xB1 = quad_perm [1,0,3,2] (xor1), 0x4E = quad_perm [2,3,0,1]
// (xor2), 0x124 = row_ror:4 (= b2-flip given b3-duplicates), 0x141 =
// row_half_mirror (l^7; == xor4 once b0,b1 are reduced), 0x128 = row_ror:8
// (exact xor8 within a 16-lane row).

// xor16 via ds_swizzle BitMode (proven r3/r4, absmax 0.0). Used ONLY in the
// lag-2 combiner now -- removed from the per-step critical path.
__device__ __forceinline__ float swz_xor16(float v) {
    return __int_as_float(__builtin_amdgcn_ds_swizzle(__float_as_int(v), 0x401F));
}

#define MAC1(hval, idx)                              \
    a0 = fmaf(hval, WhR[(idx) * 2 + 0], a0);         \
    a1 = fmaf(hval, WhR[(idx) * 2 + 1], a1);
#define MAC4(hv, j)                                  \
    MAC1((hv).x, 4 * (j) + 0)                        \
    MAC1((hv).y, 4 * (j) + 1)                        \
    MAC1((hv).z, 4 * (j) + 2)                        \
    MAC1((hv).w, 4 * (j) + 3)

// Per-step score/proj partial reduce (deferred 1 step): 2 DPP stages only
// (xor1 = b0, ror:4 = b2 via b3-duplicates). The remaining bits {b4,b5} are
// NOT reduced here -- 4 group-partials per class per wave go to pl_lds and
// the lag-2 combiner absorbs them (3 extra DPP levels there, off the
// critical path). This removes the per-step swz_xor16 + ds_bpermute serial
// LDS-pipe chain (~240 cy) that round-4 localized as part of the fixed C.
// Writers: b0=b2=b3=0 (l & 0xD == 0), 8 lanes = 2 classes x 4 groups.
#define UP_REDUCE(RING)                                                       \
    {                                                                         \
      float r = uP;                                                           \
      r += dppf<0xB1>(r);                                                     \
      r += dppf<0x124>(r);                                                    \
      if ((l & 0xD) == 0)                                                     \
        ((float*)&pl_lds[RING][(w << 2) | ((l >> 4) & 3)])[(l >> 1) & 1] = r; \
    }

// Lag-2 combiner over 32 float2 entries (8 waves x 4 groups): 5-level DPP
// tree (xor1, xor2, xor4 via half_mirror, xor8 via ror:8, xor16 via swizzle)
// -- all controls proven on this HW. Run by wave (s&7): rotates per phase,
// so no wave is a straggler.
#define PL_COMBINE(RING, SIDX)                                                \
    {                                                                         \
      float2 pp = pl_lds[RING][l & 31];                                       \
      float px = pp.x, py = pp.y;                                             \
      px += dppf<0xB1>(px);  py += dppf<0xB1>(py);                            \
      px += dppf<0x4E>(px);  py += dppf<0x4E>(py);                            \
      px += dppf<0x141>(px); py += dppf<0x141>(py);                           \
      px += dppf<0x128>(px); py += dppf<0x128>(py);                           \
      px += swz_xor16(px);   py += swz_xor16(py);                             \
      if (l == 0) part[((SIDX) << 8) + b] = make_float2(px, py);              \
    }

// Shared matvec core: 32 Wh MAC + merged k-tree (xor1 per-acc, select, then
// shared xor2+xor8 tail that also reduces xwp's duplicate-lane bits).
// Produces `hn` (r3's exact math, absmax 0.0 proven).
#define MAT_CORE(XA, XB)                                                      \
    float a0 = 0.f, a1 = 0.f;                                                 \
    MAC4(hv0, 0) MAC4(hv1, 1) MAC4(hv2, 2) MAC4(hv3, 3)                       \
    a0 += dppf<0xB1>(a0);                                                     \
    a1 += dppf<0xB1>(a1);                                                     \
    float tt = kb0b ? a1 : a0;                                                \
    float xwp = biasR;                                                        \
    xwp = fmaf((XA).x, WiC[0], xwp);                                          \
    xwp = fmaf((XA).y, WiC[1], xwp);                                          \
    xwp = fmaf((XA).z, WiC[2], xwp);                                          \
    xwp = fmaf((XA).w, WiC[3], xwp);                                          \
    xwp = fmaf((XB).x, WiC[4], xwp);                                          \
    xwp = fmaf((XB).y, WiC[5], xwp);                                          \
    xwp = fmaf((XB).z, WiC[6], xwp);                                          \
    xwp = fmaf((XB).w, WiC[7], xwp);                                          \
    tt += xwp;                                                                \
    tt += dppf<0x4E>(tt);                                                     \
    tt += dppf<0x128>(tt);                                                    \
    const float hn = tt;

// FULL step: runtime guards + full branch chain. Used only for the peeled
// first (g=0) and last (g=255) groups -- covers s==0 and s==S_-2 specials.
#define STEP_FULL(g, PH, XA, XB, CPH)                                         \
  {                                                                           \
    const int s_ = (g) * 8 + (PH);                                            \
    const float4* hsrc = (const float4*)&h0_lds[(PH) & 1][0];                 \
    float4 hv0 = hsrc[kg];                                                    \
    float4 hv1 = hsrc[kg + 8];                                                \
    float4 hv2 = hsrc[kg + 16];                                               \
    float4 hv3 = hsrc[kg + 24];                                               \
    if (s_ >= 1) UP_REDUCE(((PH) + 3) & 3)                                    \
    if (w == (PH) && s_ >= 2) PL_COMBINE(((PH) + 2) & 3, s_ - 2)              \
    MAT_CORE(XA, XB)                                                          \
    if (s_ < S_ - 2) {                                                        \
      const float4* xr = (const float4*)(xgrp + ((PH) + 2) * I_);             \
      (XA) = xr[0]; (XB) = xr[1];                                             \
    }                                                                         \
    uP = hn * (CPH);                                                          \
    float h0n;                                                                \
    if (s_ == 0)            { hstartR = hn; h0n = 0.0f; }                     \
    else if (s_ == S_ - 2)  { h0n = fast_tanh(hn + hstartR); }                \
    else if (rd == 1)       { h0n = fast_tanh(hn + h0R); }                    \
    else if (cnt == 0)      { h0n = fast_tanh(hn + htR); htR = hn; }          \
    else                    { h0n = fast_tanh(hn); }                          \
    h0R = h0n;                                                                \
    if (wmask) h0_lds[((PH) + 1) & 1][hf] = h0n;                              \
    cnt = (cnt + 1 == rd) ? 0 : cnt + 1;                                      \
    sync_lds();                                                               \
  }

// LEAN step: g in [1,254] -> s_ in [8,2039]. All s_ guards fold away;
// refill unconditional; residual select branchless (rd1 loop-invariant,
// cnt==0 uniform -> 2 cndmask + add instead of a 4-deep branch chain).
#define STEP_LEAN(g, PH, XA, XB, CPH)                                         \
  {                                                                           \
    const int s_ = (g) * 8 + (PH);                                            \
    const float4* hsrc = (const float4*)&h0_lds[(PH) & 1][0];                 \
    float4 hv0 = hsrc[kg];                                                    \
    float4 hv1 = hsrc[kg + 8];                                                \
    float4 hv2 = hsrc[kg + 16];                                               \
    float4 hv3 = hsrc[kg + 24];                                               \
    UP_REDUCE(((PH) + 3) & 3)                                                 \
    if (w == (PH)) PL_COMBINE(((PH) + 2) & 3, s_ - 2)                         \
    MAT_CORE(XA, XB)                                                          \
    {                                                                         \
      const float4* xr = (const float4*)(xgrp + ((PH) + 2) * I_);             \
      (XA) = xr[0]; (XB) = xr[1];                                             \
    }                                                                         \
    uP = hn * (CPH);                                                          \
    const bool c0 = (cnt == 0);                                               \
    float resid = rd1 ? h0R : (c0 ? htR : 0.0f);                              \
    float h0n = fast_tanh(hn + resid);                                        \
    htR = (htup && c0) ? hn : htR;                                            \
    h0R = h0n;                                                                \
    if (wmask) h0_lds[((PH) + 1) & 1][hf] = h0n;                              \
    cnt = (cnt + 1 == rd) ? 0 : cnt + 1;                                      \
    sync_lds();                                                               \
  }

// 512 threads = 8 waves per batch, 1 batch per block, 256 blocks = all CUs.
// Model (rounds 0-4, measured): wall = per-SIMD VALU issue + fixed serial
// loop C ~ 950-1000 cy that is INSENSITIVE to wave count, barrier width and
// LDS burst size (r4: halving all three changed nothing). C's attackable
// parts: the per-step swz+bperm serial LDS-pipe chain and per-step branch
// overhead -- both removed this round. waves_per_eu(2,2): 2 waves/SIMD.
__global__ __launch_bounds__(512)
__attribute__((amdgpu_waves_per_eu(2, 2)))
void rnn_kernel(
    const float* __restrict__ x, const float* __restrict__ Wi,
    const float* __restrict__ bi, const float* __restrict__ Wh,
    const float* __restrict__ bh, const float* __restrict__ Wa,
    const float* __restrict__ Wd, const int* __restrict__ rdp,
    float2* __restrict__ part)
{
    const int b = blockIdx.x;
    const int t = threadIdx.x;
    const int w = t >> 6;           // wave id 0..7
    const int l = t & 63;
    // k-group bits {0,1,3}; h-group bits {2,4,5}; duplicate-lane bits {1,3}
    const int  kg    = (l & 3) | (((l >> 3) & 1) << 2);              // 0..7
    const int  hg    = ((l >> 2) & 1) | (((l >> 4) & 1) << 1)
                     | (((l >> 5) & 1) << 2);                        // 0..7
    const int  hbase = 16 * w + 2 * hg;
    const int  hf    = hbase + (l & 1);     // this lane's final h
    const bool kb0b  = (l & 1);
    const bool wmask = ((l & 0xA) == 0);    // 16 writer lanes (distinct h)
    const int  i0x   = 8 * (((l >> 1) & 1) | (((l >> 3) & 1) << 1)); // 0,8,16,24

    __shared__ __align__(16) float h0_lds[2][H_];
    __shared__ __align__(8)  float2 pl_lds[4][32];  // ring x (8 waves x 4 grp)

    const int rd = rdp[0];
    const bool rd1  = (rd == 1);
    const bool htup = !rd1;
    if (t < H_) h0_lds[0][t] = 0.0f;

    // Wh: lane's 16 k (k = 4kg + 32j + c) x 2 h (hbase, hbase+1)
    float WhR[32];
#pragma unroll
    for (int j = 0; j < 4; ++j)
#pragma unroll
        for (int c = 0; c < 4; ++c) {
            int k = 4 * kg + 32 * j + c;
            float2 wv = *(const float2*)(Wh + (size_t)k * H_ + hbase);
            WhR[(4 * j + c) * 2 + 0] = wv.x;
            WhR[(4 * j + c) * 2 + 1] = wv.y;
        }
    // Wi: this lane's i-slice (8 of 32) for its h
    float WiC[8];
#pragma unroll
    for (int i = 0; i < 8; ++i) WiC[i] = Wi[(size_t)(i0x + i) * H_ + hf];
    const float biasR = wmask ? (bi[hf] + bh[hf]) : 0.0f;  // added once per h

    // Per-phase score/proj coefficient: class bit b1 selects pv (Wa) or qv
    // (Wd column for this b, phase s&7). Class-preserving reduce -> each h
    // counted exactly once per class, no duplication scale.
    const bool clsq = (l >> 1) & 1;   // b1: 0 = pv lane, 1 = qv lane
    const float waC = Wa[hf];
    float cph[8];
#pragma unroll
    for (int K = 0; K < 8; ++K)
        cph[K] = clsq ? Wd[(K << 15) + (b << 7) + hf] : waC;

    // x group pointer: rows of this group reachable via imm offsets
    const float* xgrp = x + (size_t)b * (S_ * I_) + i0x;
    float4 xA0 = ((const float4*)xgrp)[0];
    float4 xB0 = ((const float4*)xgrp)[1];
    float4 xA1 = ((const float4*)(xgrp + I_))[0];
    float4 xB1 = ((const float4*)(xgrp + I_))[1];

    sync_lds();

    float htR = 0.f, hstartR = 0.f, h0R = 0.f;
    float uP = 0.f;   // previous step's (hn * coef), reduced next step
    int cnt = 0;      // s % rd, incremental

    // g = 0 peeled (covers s==0 special + warm-up guards)
    {
        STEP_FULL(0, 0, xA0, xB0, cph[0])
        STEP_FULL(0, 1, xA1, xB1, cph[1])
        STEP_FULL(0, 2, xA0, xB0, cph[2])
        STEP_FULL(0, 3, xA1, xB1, cph[3])
        STEP_FULL(0, 4, xA0, xB0, cph[4])
        STEP_FULL(0, 5, xA1, xB1, cph[5])
        STEP_FULL(0, 6, xA0, xB0, cph[6])
        STEP_FULL(0, 7, xA1, xB1, cph[7])
        xgrp += 8 * I_;
    }
    // hot loop: g in [1, 254], all guards folded away
    for (int g = 1; g < 255; ++g) {
        STEP_LEAN(g, 0, xA0, xB0, cph[0])
        STEP_LEAN(g, 1, xA1, xB1, cph[1])
        STEP_LEAN(g, 2, xA0, xB0, cph[2])
        STEP_LEAN(g, 3, xA1, xB1, cph[3])
        STEP_LEAN(g, 4, xA0, xB0, cph[4])
        STEP_LEAN(g, 5, xA1, xB1, cph[5])
        STEP_LEAN(g, 6, xA0, xB0, cph[6])
        STEP_LEAN(g, 7, xA1, xB1, cph[7])
        xgrp += 8 * I_;
    }
    // g = 255 peeled (covers s==S_-2 special + refill clamp)
    {
        STEP_FULL(255, 0, xA0, xB0, cph[0])
        STEP_FULL(255, 1, xA1, xB1, cph[1])
        STEP_FULL(255, 2, xA0, xB0, cph[2])
        STEP_FULL(255, 3, xA1, xB1, cph[3])
        STEP_FULL(255, 4, xA0, xB0, cph[4])
        STEP_FULL(255, 5, xA1, xB1, cph[5])
        STEP_FULL(255, 6, xA0, xB0, cph[6])
        STEP_FULL(255, 7, xA1, xB1, cph[7])
    }

    // epilogue: reduce s = S-1's partial into ring 3 ((S_-1)&3), then
    // combine rings 2 (s = S-2, written at top of step S-1) and 3.
    UP_REDUCE(3)
    sync_lds();
    if (w == 0) PL_COMBINE(2, S_ - 2)
    if (w == 1) PL_COMBINE(3, S_ - 1)
}

// out[r] = bd + sum_{f in chunk r} softmax(score)_f * d_f, chunk = 2048 flat
// (s,b) pairs with s in [8r,8r+8). ba is softmax-invariant -> omitted.
__global__ __launch_bounds__(256) void attn_kernel(
    const float2* __restrict__ part, const float* __restrict__ bd,
    float* __restrict__ out)
{
    const int r = blockIdx.x;
    const int t = threadIdx.x;
    float sc[8], dv[8];
    float mx = -1e30f;
#pragma unroll
    for (int u = 0; u < 8; ++u) {
        int f = (r << 11) + (u << 8) + t;
        float2 a = part[f];
        sc[u] = a.x;
        dv[u] = a.y;
        mx = fmaxf(mx, sc[u]);
    }
    __shared__ float redm[4], redz[4], redw[4];
#pragma unroll
    for (int off = 32; off > 0; off >>= 1) mx = fmaxf(mx, __shfl_xor(mx, off, 64));
    if ((t & 63) == 0) redm[t >> 6] = mx;
    __syncthreads();
    mx = fmaxf(fmaxf(redm[0], redm[1]), fmaxf(redm[2], redm[3]));
    float z = 0.f, wv = 0.f;
#pragma unroll
    for (int u = 0; u < 8; ++u) {
        float e = __expf(sc[u] - mx);
        z += e;
        wv += e * dv[u];
    }
#pragma unroll
    for (int off = 32; off > 0; off >>= 1) {
        z += __shfl_xor(z, off, 64);
        wv += __shfl_xor(wv, off, 64);
    }
    if ((t & 63) == 0) { redz[t >> 6] = z; redw[t >> 6] = wv; }
    __syncthreads();
    if (t == 0) {
        float Z = redz[0] + redz[1] + redz[2] + redz[3];
        float W = redw[0] + redw[1] + redw[2] + redw[3];
        out[r] = bd[0] + W / Z;
    }
}

extern "C" void kernel_launch(void* const* d_in, const int* in_sizes, int n_in,
                              void* d_out, int out_size, void* d_ws, size_t ws_size,
                              hipStream_t stream) {
    const float* x  = (const float*)d_in[0];
    const float* Wi = (const float*)d_in[1];
    const float* bi = (const float*)d_in[2];
    const float* Wh = (const float*)d_in[3];
    const float* bh = (const float*)d_in[4];
    const float* Wa = (const float*)d_in[5];
    // d_in[6] = ba: constant shift inside each softmax chunk -> no effect.
    const float* Wd = (const float*)d_in[7];
    const float* bd = (const float*)d_in[8];
    const int*  rdp = (const int*)d_in[9];

    // Workspace: one (S*B) float2 array of combined {score, d} (4 MiB)
    float2* part = (float2*)d_ws;

    rnn_kernel<<<B_, 512, 0, stream>>>(x, Wi, bi, Wh, bh, Wa, Wd, rdp, part);
    attn_kernel<<<B_, 256, 0, stream>>>(part, bd, (float*)d_out);
}

// Round 6
// 863.351 us; speedup vs baseline: 1.2497x; 1.0765x over previous
//
#include <hip/hip_runtime.h>
#include <math.h>

// Problem constants (fixed by the reference): B=256, S=2048, I=32, H=128, O=1
#define B_ 256
#define S_ 2048
#define I_ 32
#define H_ 128

typedef float v2f __attribute__((ext_vector_type(2)));
__device__ __forceinline__ v2f mk2(float a, float b) { v2f r; r.x = a; r.y = b; return r; }

// Packed fp32 FMA (VOP3P, gfx90a+ CDNA line): d.{x,y} += a.{x,y} * b.{x,y}.
// _lo/_hi variants splat one half of `a` to both lanes via op_sel -- used to
// broadcast a single h value against a (w_h0, w_h1) pair without splat movs.
__device__ __forceinline__ void pk_fma(v2f& d, v2f a, v2f b) {
    asm("v_pk_fma_f32 %0, %1, %2, %0" : "+v"(d) : "v"(a), "v"(b));
}
__device__ __forceinline__ void pk_fma_lo(v2f& d, v2f a, v2f b) {
    asm("v_pk_fma_f32 %0, %1, %2, %0 op_sel:[0,0,0] op_sel_hi:[0,1,1]"
        : "+v"(d) : "v"(a), "v"(b));
}
__device__ __forceinline__ void pk_fma_hi(v2f& d, v2f a, v2f b) {
    asm("v_pk_fma_f32 %0, %1, %2, %0 op_sel:[1,0,0] op_sel_hi:[1,1,1]"
        : "+v"(d) : "v"(a), "v"(b));
}

// Barrier WITHOUT vmcnt(0) drain (HIP __syncthreads waits vmcnt(0) before
// s_barrier, stalling on in-flight global prefetch/stores every step).
// LDS visibility only needs lgkmcnt(0).
__device__ __forceinline__ void sync_lds() {
    asm volatile("" ::: "memory");
    asm volatile("s_waitcnt lgkmcnt(0)" ::: "memory");
    __builtin_amdgcn_s_barrier();
    asm volatile("" ::: "memory");
}

// tanh(z) = 1 - 2/(e^{2z}+1); exact limits at +-inf, abs err ~1e-7.
__device__ __forceinline__ float fast_tanh(float z) {
    float e = __expf(2.0f * z);
    return 1.0f - 2.0f / (e + 1.0f);
}

template <int CTRL>
__device__ __forceinline__ float dppf(float v) {
    return __int_as_float(__builtin_amdgcn_update_dpp(
        0, __float_as_int(v), CTRL, 0xF, 0xF, false));
}
// DPP controls: 0xB1 = quad_perm [1,0,3,2] (xor1), 0x4E = quad_perm [2,3,0,1]
// (xor2), 0x124 = row_ror:4 (= b2-flip given b3-duplicates), 0x141 =
// row_half_mirror (l^7; == xor4 once b0,b1 are reduced), 0x128 = row_ror:8
// (exact xor8 within a 16-lane row).

// xor16 via ds_swizzle BitMode (proven r3-r5, absmax 0.0). Only in the lag-2
// combiner -- off the per-step critical path.
__device__ __forceinline__ float swz_xor16(float v) {
    return __int_as_float(__builtin_amdgcn_ds_swizzle(__float_as_int(v), 0x401F));
}

// Packed Wh MACs for one float4 of h values (4 k): 4 pk_fma instead of 8
// scalar fma. accA takes k-pair {4q,4q+1} (h from hv.xy), accB {4q+2,4q+3}
// (hv.zw) -- two 8-deep chains, summed once at the end.
#define PKQ(hv, q)                                                \
    pk_fma_lo(accA, mk2((hv).x, (hv).y), WhP[4 * (q) + 0]);       \
    pk_fma_hi(accA, mk2((hv).x, (hv).y), WhP[4 * (q) + 1]);       \
    pk_fma_lo(accB, mk2((hv).z, (hv).w), WhP[4 * (q) + 2]);       \
    pk_fma_hi(accB, mk2((hv).z, (hv).w), WhP[4 * (q) + 3]);

// Per-step score/proj partial reduce (deferred 1 step): 2 DPP stages only;
// remaining bits {b4,b5} go to pl_lds as 4 group-partials per class per wave
// and the lag-2 combiner absorbs them. (r5 win, kept.)
#define UP_REDUCE(RING)                                                       \
    {                                                                         \
      float r = uP;                                                           \
      r += dppf<0xB1>(r);                                                     \
      r += dppf<0x124>(r);                                                    \
      if ((l & 0xD) == 0)                                                     \
        ((float*)&pl_lds[RING][(w << 2) | ((l >> 4) & 3)])[(l >> 1) & 1] = r; \
    }

// Lag-2 combiner over 32 float2 entries (8 waves x 4 groups): 5-level tree
// (xor1, xor2, xor4 via half_mirror, xor8 via ror:8, xor16 via swizzle).
// Run by wave (s&7): rotates per phase, no fixed straggler.
#define PL_COMBINE(RING, SIDX)                                                \
    {                                                                         \
      float2 pp = pl_lds[RING][l & 31];                                       \
      float px = pp.x, py = pp.y;                                             \
      px += dppf<0xB1>(px);  py += dppf<0xB1>(py);                            \
      px += dppf<0x4E>(px);  py += dppf<0x4E>(py);                            \
      px += dppf<0x141>(px); py += dppf<0x141>(py);                           \
      px += dppf<0x128>(px); py += dppf<0x128>(py);                           \
      px += swz_xor16(px);   py += swz_xor16(py);                             \
      if (l == 0) part[((SIDX) << 8) + b] = make_float2(px, py);              \
    }

// Shared matvec core: xw (4 pk_fma, bias folded into init) + 16 pk_fma Wh
// MACs + merged k-tree (xor1 per-half, select, shared xor2+xor8 tail).
// Same math as r5 (reassociated only at the accA/accB split and the xw
// even/odd-i split; reference order differs anyway).
#define MAT_CORE(XA, XB)                                                      \
    v2f xw01 = mk2(biasR, 0.0f);                                              \
    pk_fma(xw01, mk2((XA).x, (XA).y), WiP[0]);                                \
    pk_fma(xw01, mk2((XA).z, (XA).w), WiP[1]);                                \
    pk_fma(xw01, mk2((XB).x, (XB).y), WiP[2]);                                \
    pk_fma(xw01, mk2((XB).z, (XB).w), WiP[3]);                                \
    v2f accA = mk2(0.0f, 0.0f), accB = mk2(0.0f, 0.0f);                       \
    PKQ(hv0, 0) PKQ(hv1, 1) PKQ(hv2, 2) PKQ(hv3, 3)                           \
    float a0 = accA.x + accB.x;                                               \
    float a1 = accA.y + accB.y;                                               \
    a0 += dppf<0xB1>(a0);                                                     \
    a1 += dppf<0xB1>(a1);                                                     \
    float tt = kb0b ? a1 : a0;                                                \
    tt += xw01.x + xw01.y;                                                    \
    tt += dppf<0x4E>(tt);                                                     \
    tt += dppf<0x128>(tt);                                                    \
    const float hn = tt;

// FULL step: runtime guards + full branch chain. Peeled first (g=0) and
// last (g=255) groups only -- covers s==0 and s==S_-2 specials, any rd.
#define STEP_FULL(g, PH, XA, XB, CPH)                                         \
  {                                                                           \
    const int s_ = (g) * 8 + (PH);                                            \
    const float4* hsrc = (const float4*)&h0_lds[(PH) & 1][0];                 \
    float4 hv0 = hsrc[kg];                                                    \
    float4 hv1 = hsrc[kg + 8];                                                \
    float4 hv2 = hsrc[kg + 16];                                               \
    float4 hv3 = hsrc[kg + 24];                                               \
    if (s_ >= 1) UP_REDUCE(((PH) + 3) & 3)                                    \
    if (w == (PH) && s_ >= 2) PL_COMBINE(((PH) + 2) & 3, s_ - 2)              \
    MAT_CORE(XA, XB)                                                          \
    if (s_ < S_ - 2) {                                                        \
      const float4* xr = (const float4*)(xgrp + ((PH) + 2) * I_);             \
      (XA) = xr[0]; (XB) = xr[1];                                             \
    }                                                                         \
    uP = hn * (CPH);                                                          \
    float h0n;                                                                \
    if (s_ == 0)            { hstartR = hn; h0n = 0.0f; }                     \
    else if (s_ == S_ - 2)  { h0n = fast_tanh(hn + hstartR); }                \
    else if (rd == 1)       { h0n = fast_tanh(hn + h0R); }                    \
    else if (cnt == 0)      { h0n = fast_tanh(hn + htR); htR = hn; }          \
    else                    { h0n = fast_tanh(hn); }                          \
    h0R = h0n;                                                                \
    if (wmask) h0_lds[((PH) + 1) & 1][hf] = h0n;                              \
    cnt = (cnt + 1 == rd) ? 0 : cnt + 1;                                      \
    sync_lds();                                                               \
  }

// LEAN4: rd==4 specialization, g in [1,254]. s%4 == PH%4 is COMPILE-TIME
// (8-wide unroll, 8%4==0): no cnt bookkeeping, no residual cndmasks --
// PH%4==0 steps do tanh(hn+htR) & htR=hn; others tanh(hn). (resDepth==4 is
// the bench value; generic STEP_LEAN below handles any rd.)
#define STEP_LEAN4(g, PH, XA, XB, CPH)                                        \
  {                                                                           \
    const float4* hsrc = (const float4*)&h0_lds[(PH) & 1][0];                 \
    float4 hv0 = hsrc[kg];                                                    \
    float4 hv1 = hsrc[kg + 8];                                                \
    float4 hv2 = hsrc[kg + 16];                                               \
    float4 hv3 = hsrc[kg + 24];                                               \
    UP_REDUCE(((PH) + 3) & 3)                                                 \
    if (w == (PH)) PL_COMBINE(((PH) + 2) & 3, (g) * 8 + (PH) - 2)             \
    MAT_CORE(XA, XB)                                                          \
    {                                                                         \
      const float4* xr = (const float4*)(xgrp + ((PH) + 2) * I_);             \
      (XA) = xr[0]; (XB) = xr[1];                                             \
    }                                                                         \
    uP = hn * (CPH);                                                          \
    float h0n;                                                                \
    if (((PH) & 3) == 0) { h0n = fast_tanh(hn + htR); htR = hn; }             \
    else                 { h0n = fast_tanh(hn); }                             \
    if (wmask) h0_lds[((PH) + 1) & 1][hf] = h0n;                              \
    sync_lds();                                                               \
  }

// Generic LEAN step (any rd): branchless residual, runtime cnt.
#define STEP_LEAN(g, PH, XA, XB, CPH)                                         \
  {                                                                           \
    const float4* hsrc = (const float4*)&h0_lds[(PH) & 1][0];                 \
    float4 hv0 = hsrc[kg];                                                    \
    float4 hv1 = hsrc[kg + 8];                                                \
    float4 hv2 = hsrc[kg + 16];                                               \
    float4 hv3 = hsrc[kg + 24];                                               \
    UP_REDUCE(((PH) + 3) & 3)                                                 \
    if (w == (PH)) PL_COMBINE(((PH) + 2) & 3, (g) * 8 + (PH) - 2)             \
    MAT_CORE(XA, XB)                                                          \
    {                                                                         \
      const float4* xr = (const float4*)(xgrp + ((PH) + 2) * I_);             \
      (XA) = xr[0]; (XB) = xr[1];                                             \
    }                                                                         \
    uP = hn * (CPH);                                                          \
    const bool c0 = (cnt == 0);                                               \
    float resid = rd1 ? h0R : (c0 ? htR : 0.0f);                              \
    float h0n = fast_tanh(hn + resid);                                        \
    htR = (htup && c0) ? hn : htR;                                            \
    h0R = h0n;                                                                \
    if (wmask) h0_lds[((PH) + 1) & 1][hf] = h0n;                              \
    cnt = (cnt + 1 == rd) ? 0 : cnt + 1;                                      \
    sync_lds();                                                               \
  }

// 512 threads = 8 waves per batch, 1 batch per block, 256 blocks = all CUs.
// Model (rounds 0-5, measured): effective clock ~1.7 GHz; wall 763 cy/step
// = per-SIMD VALU issue ~460 cy (matches VALUBusy 61%) + C ~300 cy
// (barrier + LDS-read latency + chains, mostly overlapped). ISSUE-BOUND:
// this round halves the FMA instruction count via v_pk_fma_f32 (VOP3P,
// op_sel splat for the h broadcast) and folds rd==4 bookkeeping away.
__global__ __launch_bounds__(512)
__attribute__((amdgpu_waves_per_eu(2, 2)))
void rnn_kernel(
    const float* __restrict__ x, const float* __restrict__ Wi,
    const float* __restrict__ bi, const float* __restrict__ Wh,
    const float* __restrict__ bh, const float* __restrict__ Wa,
    const float* __restrict__ Wd, const int* __restrict__ rdp,
    float2* __restrict__ part)
{
    const int b = blockIdx.x;
    const int t = threadIdx.x;
    const int w = t >> 6;           // wave id 0..7
    const int l = t & 63;
    // k-group bits {0,1,3}; h-group bits {2,4,5}; duplicate-lane bits {1,3}
    const int  kg    = (l & 3) | (((l >> 3) & 1) << 2);              // 0..7
    const int  hg    = ((l >> 2) & 1) | (((l >> 4) & 1) << 1)
                     | (((l >> 5) & 1) << 2);                        // 0..7
    const int  hbase = 16 * w + 2 * hg;
    const int  hf    = hbase + (l & 1);     // this lane's final h
    const bool kb0b  = (l & 1);
    const bool wmask = ((l & 0xA) == 0);    // 16 writer lanes (distinct h)
    const int  i0x   = 8 * (((l >> 1) & 1) | (((l >> 3) & 1) << 1)); // 0,8,16,24

    __shared__ __align__(16) float h0_lds[2][H_];
    __shared__ __align__(8)  float2 pl_lds[4][32];  // ring x (8 waves x 4 grp)

    const int rd = rdp[0];
    const bool rd1  = (rd == 1);
    const bool htup = !rd1;
    if (t < H_) h0_lds[0][t] = 0.0f;

    // Wh: lane's 16 k (k = 4kg + 32j + c) x 2 h (hbase, hbase+1), as v2f
    v2f WhP[16];
#pragma unroll
    for (int j = 0; j < 4; ++j)
#pragma unroll
        for (int c = 0; c < 4; ++c) {
            int k = 4 * kg + 32 * j + c;
            float2 wv = *(const float2*)(Wh + (size_t)k * H_ + hbase);
            WhP[4 * j + c] = mk2(wv.x, wv.y);
        }
    // Wi: this lane's i-slice (8 of 32) for its h, packed as 4 i-pairs
    v2f WiP[4];
#pragma unroll
    for (int j = 0; j < 4; ++j) {
        float w0 = Wi[(size_t)(i0x + 2 * j) * H_ + hf];
        float w1 = Wi[(size_t)(i0x + 2 * j + 1) * H_ + hf];
        WiP[j] = mk2(w0, w1);
    }
    const float biasR = wmask ? (bi[hf] + bh[hf]) : 0.0f;  // added once per h

    // Per-phase score/proj coefficient: class bit b1 selects pv (Wa) or qv
    // (Wd column for this b, phase s&7). Class-preserving reduce -> each h
    // counted exactly once per class, no duplication scale.
    const bool clsq = (l >> 1) & 1;   // b1: 0 = pv lane, 1 = qv lane
    const float waC = Wa[hf];
    float cph[8];
#pragma unroll
    for (int K = 0; K < 8; ++K)
        cph[K] = clsq ? Wd[(K << 15) + (b << 7) + hf] : waC;

    // x group pointer: rows of this group reachable via imm offsets
    const float* xgrp = x + (size_t)b * (S_ * I_) + i0x;
    float4 xA0 = ((const float4*)xgrp)[0];
    float4 xB0 = ((const float4*)xgrp)[1];
    float4 xA1 = ((const float4*)(xgrp + I_))[0];
    float4 xB1 = ((const float4*)(xgrp + I_))[1];

    sync_lds();

    float htR = 0.f, hstartR = 0.f, h0R = 0.f;
    float uP = 0.f;   // previous step's (hn * coef), reduced next step
    int cnt = 0;      // s % rd, incremental

    // g = 0 peeled (covers s==0 special + warm-up guards)
    {
        STEP_FULL(0, 0, xA0, xB0, cph[0])
        STEP_FULL(0, 1, xA1, xB1, cph[1])
        STEP_FULL(0, 2, xA0, xB0, cph[2])
        STEP_FULL(0, 3, xA1, xB1, cph[3])
        STEP_FULL(0, 4, xA0, xB0, cph[4])
        STEP_FULL(0, 5, xA1, xB1, cph[5])
        STEP_FULL(0, 6, xA0, xB0, cph[6])
        STEP_FULL(0, 7, xA1, xB1, cph[7])
        xgrp += 8 * I_;
    }
    if (rd == 4) {
        // hot loop, rd==4 (the bench value): cnt == PH%4 compile-time
        for (int g = 1; g < 255; ++g) {
            STEP_LEAN4(g, 0, xA0, xB0, cph[0])
            STEP_LEAN4(g, 1, xA1, xB1, cph[1])
            STEP_LEAN4(g, 2, xA0, xB0, cph[2])
            STEP_LEAN4(g, 3, xA1, xB1, cph[3])
            STEP_LEAN4(g, 4, xA0, xB0, cph[4])
            STEP_LEAN4(g, 5, xA1, xB1, cph[5])
            STEP_LEAN4(g, 6, xA0, xB0, cph[6])
            STEP_LEAN4(g, 7, xA1, xB1, cph[7])
            xgrp += 8 * I_;
        }
        cnt = 0;   // 2040 % 4 == 0, for the peeled tail
    } else {
        // generic hot loop (any rd, incl. rd==1)
        for (int g = 1; g < 255; ++g) {
            STEP_LEAN(g, 0, xA0, xB0, cph[0])
            STEP_LEAN(g, 1, xA1, xB1, cph[1])
            STEP_LEAN(g, 2, xA0, xB0, cph[2])
            STEP_LEAN(g, 3, xA1, xB1, cph[3])
            STEP_LEAN(g, 4, xA0, xB0, cph[4])
            STEP_LEAN(g, 5, xA1, xB1, cph[5])
            STEP_LEAN(g, 6, xA0, xB0, cph[6])
            STEP_LEAN(g, 7, xA1, xB1, cph[7])
            xgrp += 8 * I_;
        }
    }
    // g = 255 peeled (covers s==S_-2 special + refill clamp)
    {
        STEP_FULL(255, 0, xA0, xB0, cph[0])
        STEP_FULL(255, 1, xA1, xB1, cph[1])
        STEP_FULL(255, 2, xA0, xB0, cph[2])
        STEP_FULL(255, 3, xA1, xB1, cph[3])
        STEP_FULL(255, 4, xA0, xB0, cph[4])
        STEP_FULL(255, 5, xA1, xB1, cph[5])
        STEP_FULL(255, 6, xA0, xB0, cph[6])
        STEP_FULL(255, 7, xA1, xB1, cph[7])
    }

    // epilogue: reduce s = S-1's partial into ring 3 ((S_-1)&3), then
    // combine rings 2 (s = S-2, written at top of step S-1) and 3.
    UP_REDUCE(3)
    sync_lds();
    if (w == 0) PL_COMBINE(2, S_ - 2)
    if (w == 1) PL_COMBINE(3, S_ - 1)
}

// out[r] = bd + sum_{f in chunk r} softmax(score)_f * d_f, chunk = 2048 flat
// (s,b) pairs with s in [8r,8r+8). ba is softmax-invariant -> omitted.
__global__ __launch_bounds__(256) void attn_kernel(
    const float2* __restrict__ part, const float* __restrict__ bd,
    float* __restrict__ out)
{
    const int r = blockIdx.x;
    const int t = threadIdx.x;
    float sc[8], dv[8];
    float mx = -1e30f;
#pragma unroll
    for (int u = 0; u < 8; ++u) {
        int f = (r << 11) + (u << 8) + t;
        float2 a = part[f];
        sc[u] = a.x;
        dv[u] = a.y;
        mx = fmaxf(mx, sc[u]);
    }
    __shared__ float redm[4], redz[4], redw[4];
#pragma unroll
    for (int off = 32; off > 0; off >>= 1) mx = fmaxf(mx, __shfl_xor(mx, off, 64));
    if ((t & 63) == 0) redm[t >> 6] = mx;
    __syncthreads();
    mx = fmaxf(fmaxf(redm[0], redm[1]), fmaxf(redm[2], redm[3]));
    float z = 0.f, wv = 0.f;
#pragma unroll
    for (int u = 0; u < 8; ++u) {
        float e = __expf(sc[u] - mx);
        z += e;
        wv += e * dv[u];
    }
#pragma unroll
    for (int off = 32; off > 0; off >>= 1) {
        z += __shfl_xor(z, off, 64);
        wv += __shfl_xor(wv, off, 64);
    }
    if ((t & 63) == 0) { redz[t >> 6] = z; redw[t >> 6] = wv; }
    __syncthreads();
    if (t == 0) {
        float Z = redz[0] + redz[1] + redz[2] + redz[3];
        float W = redw[0] + redw[1] + redw[2] + redw[3];
        out[r] = bd[0] + W / Z;
    }
}

extern "C" void kernel_launch(void* const* d_in, const int* in_sizes, int n_in,
                              void* d_out, int out_size, void* d_ws, size_t ws_size,
                              hipStream_t stream) {
    const float* x  = (const float*)d_in[0];
    const float* Wi = (const float*)d_in[1];
    const float* bi = (const float*)d_in[2];
    const float* Wh = (const float*)d_in[3];
    const float* bh = (const float*)d_in[4];
    const float* Wa = (const float*)d_in[5];
    // d_in[6] = ba: constant shift inside each softmax chunk -> no effect.
    const float* Wd = (const float*)d_in[7];
    const float* bd = (const float*)d_in[8];
    const int*  rdp = (const int*)d_in[9];

    // Workspace: one (S*B) float2 array of combined {score, d} (4 MiB)
    float2* part = (float2*)d_ws;

    rnn_kernel<<<B_, 512, 0, stream>>>(x, Wi, bi, Wh, bh, Wa, Wd, rdp, part);
    attn_kernel<<<B_, 256, 0, stream>>>(part, bd, (float*)d_out);
}

// Round 8
// 863.071 us; speedup vs baseline: 1.2502x; 1.0003x over previous
//
#include <hip/hip_runtime.h>
#include <math.h>

// Problem constants (fixed by the reference): B=256, S=2048, I=32, H=128, O=1
#define B_ 256
#define S_ 2048
#define I_ 32
#define H_ 128

typedef float v2f __attribute__((ext_vector_type(2)));
__device__ __forceinline__ v2f mk2(float a, float b) { v2f r; r.x = a; r.y = b; return r; }

// Packed fp32 FMA (VOP3P, gfx90a+ CDNA line): d.{x,y} += a.{x,y} * b.{x,y}.
// _lo/_hi variants splat one half of `a` to both lanes via op_sel -- used to
// broadcast a single value against a weight pair without splat movs.
__device__ __forceinline__ void pk_fma_lo(v2f& d, v2f a, v2f b) {
    asm("v_pk_fma_f32 %0, %1, %2, %0 op_sel:[0,0,0] op_sel_hi:[0,1,1]"
        : "+v"(d) : "v"(a), "v"(b));
}
__device__ __forceinline__ void pk_fma_hi(v2f& d, v2f a, v2f b) {
    asm("v_pk_fma_f32 %0, %1, %2, %0 op_sel:[1,0,0] op_sel_hi:[1,1,1]"
        : "+v"(d) : "v"(a), "v"(b));
}

// Barrier WITHOUT vmcnt(0) drain (HIP __syncthreads waits vmcnt(0) before
// s_barrier, stalling on in-flight global prefetch/stores every step).
// LDS visibility only needs lgkmcnt(0).
__device__ __forceinline__ void sync_lds() {
    asm volatile("" ::: "memory");
    asm volatile("s_waitcnt lgkmcnt(0)" ::: "memory");
    __builtin_amdgcn_s_barrier();
    asm volatile("" ::: "memory");
}

// tanh(z) = 1 - 2/(e^{2z}+1); exact limits at +-inf, abs err ~1e-7.
__device__ __forceinline__ float fast_tanh(float z) {
    float e = __expf(2.0f * z);
    return 1.0f - 2.0f / (e + 1.0f);
}

template <int CTRL>
__device__ __forceinline__ float dppf(float v) {
    return __int_as_float(__builtin_amdgcn_update_dpp(
        0, __float_as_int(v), CTRL, 0xF, 0xF, false));
}
// DPP controls: 0xB1 = quad_perm [1,0,3,2] (xor1), 0x4E = quad_perm [2,3,0,1]
// (xor2), 0x141 = row_half_mirror (l^7), 0x128 = row_ror:8 (l^8 in 16-row).

// xor16 via ds_swizzle BitMode (proven r3-r6, absmax ~0). Only in the lag-2
// combiner -- off the per-step critical path.
__device__ __forceinline__ float swz_xor16(float v) {
    return __int_as_float(__builtin_amdgcn_ds_swizzle(__float_as_int(v), 0x401F));
}

// h0 LDS layout: 16 chunks of 8 h values, chunk pitch 12 floats (48B).
// 48B stride => 16 distinct b128 addrs alias banks only 2-way (free, m136);
// the 4 lanes sharing a kg4 read the SAME addr (broadcast, no conflict).
#define CHP 12

// Packed Wh MACs for one float4 of h0 (4 consecutive k): 8 pk_fma covering
// 4 h outputs. acc01 = h-pair (hb,hb+1), acc23 = (hb+2,hb+3).
#define PKD(hv, base)                                             \
    pk_fma_lo(acc01, mk2((hv).x, (hv).y), W01[(base) + 0]);       \
    pk_fma_lo(acc23, mk2((hv).x, (hv).y), W23[(base) + 0]);       \
    pk_fma_hi(acc01, mk2((hv).x, (hv).y), W01[(base) + 1]);       \
    pk_fma_hi(acc23, mk2((hv).x, (hv).y), W23[(base) + 1]);       \
    pk_fma_lo(acc01, mk2((hv).z, (hv).w), W01[(base) + 2]);       \
    pk_fma_lo(acc23, mk2((hv).z, (hv).w), W23[(base) + 2]);       \
    pk_fma_hi(acc01, mk2((hv).z, (hv).w), W01[(base) + 3]);       \
    pk_fma_hi(acc23, mk2((hv).z, (hv).w), W23[(base) + 3]);

// Per-step score/proj partial reduce (deferred 1 step): 2 DPP stages
// (xor1 = b0, xor2 = b1 -- the role bits, summing the 4 roles' h).
// Remaining bits {b4,b5} go to pl_lds as 4 group-partials per class per
// wave; the lag-2 combiner absorbs them. Class bit = b2 (dup), spare dup =
// b3. Writers: b0=b1=b3=0 -> (l & 0xB) == 0, 8 lanes = 2 classes x 4 groups.
#define UP_REDUCE(RING)                                                       \
    {                                                                         \
      float r = uP;                                                           \
      r += dppf<0xB1>(r);                                                     \
      r += dppf<0x4E>(r);                                                     \
      if ((l & 0xB) == 0)                                                     \
        ((float*)&pl_lds[RING][(w << 2) | ((l >> 4) & 3)])[(l >> 2) & 1] = r; \
    }

// Lag-2 combiner over 32 float2 entries (8 waves x 4 groups): 5-level tree
// (xor1, xor2, xor4 via half_mirror, xor8 via ror:8, xor16 via swizzle).
// Run by wave (s&7): rotates per phase, no fixed straggler.
#define PL_COMBINE(RING, SIDX)                                                \
    {                                                                         \
      float2 pp = pl_lds[RING][l & 31];                                       \
      float px = pp.x, py = pp.y;                                             \
      px += dppf<0xB1>(px);  py += dppf<0xB1>(py);                            \
      px += dppf<0x4E>(px);  py += dppf<0x4E>(py);                            \
      px += dppf<0x141>(px); py += dppf<0x141>(py);                           \
      px += dppf<0x128>(px); py += dppf<0x128>(py);                           \
      px += swz_xor16(px);   py += swz_xor16(py);                             \
      if (l == 0) part[((SIDX) << 8) + b] = make_float2(px, py);              \
    }

// Matvec core, 4h x 8k per lane: TWO ds_read_b128 (vs r6's four) -- the
// read-halving lever. Lane bits: k-group = b0..b3 (kg4, 16 groups x 8 k),
// h-group = b4,b5; the lane's final h role = b0 + 2*b1.
// x.Wi (i-chunk of 2 = {2kg4, 2kg4+1}) and the bias (gated kg4==0) are
// FOLDED INTO THE ACC INIT so they ride the same reduction tree.
// Tree (r7-bugfix): stage0 = PURE half_mirror (mask 7) on all 4 accs --
// BEFORE any role select, so it never mixes h; then xor1 (+sel b0),
// xor2 (+sel b1), xor8 (pure, b3). Span {7,1,2}+{8} covers all 16 k-groups;
// bias (at kg4==0 only) enters exactly once -- verified by mask expansion.
#define MAT_CORE(XS)                                                          \
    v2f acc01 = bias01, acc23 = bias23;                                       \
    pk_fma_lo(acc01, mk2((XS).x, (XS).y), WiF01[0]);                          \
    pk_fma_hi(acc01, mk2((XS).x, (XS).y), WiF01[1]);                          \
    pk_fma_lo(acc23, mk2((XS).x, (XS).y), WiF23[0]);                          \
    pk_fma_hi(acc23, mk2((XS).x, (XS).y), WiF23[1]);                          \
    PKD(hvA, 0) PKD(hvB, 4)                                                   \
    float p0 = acc01.x + dppf<0x141>(acc01.x);                                \
    float p1 = acc01.y + dppf<0x141>(acc01.y);                                \
    float p2 = acc23.x + dppf<0x141>(acc23.x);                                \
    float p3 = acc23.y + dppf<0x141>(acc23.y);                                \
    float s01x = p0 + dppf<0xB1>(p0);                                         \
    float s01y = p1 + dppf<0xB1>(p1);                                         \
    float s23x = p2 + dppf<0xB1>(p2);                                         \
    float s23y = p3 + dppf<0xB1>(p3);                                         \
    float t0 = kb0 ? s01y : s01x;                                             \
    float t1 = kb0 ? s23y : s23x;                                             \
    t0 += dppf<0x4E>(t0);                                                     \
    t1 += dppf<0x4E>(t1);                                                     \
    float tt = kb1 ? t1 : t0;                                                 \
    tt += dppf<0x128>(tt);                                                    \
    const float hn = tt;

// FULL step: runtime guards + full branch chain. Peeled first (g=0) and
// last (g=255) groups only -- covers s==0 and s==S_-2 specials, any rd.
#define STEP_FULL(g, PH, XS, CPH)                                             \
  {                                                                           \
    const int s_ = (g) * 8 + (PH);                                            \
    const float* hb = &h0_lds[(PH) & 1][0];                                   \
    float4 hvA = *(const float4*)(hb + rdoff);                                \
    float4 hvB = *(const float4*)(hb + rdoff + 4);                            \
    if (s_ >= 1) UP_REDUCE(((PH) + 3) & 3)                                    \
    if (w == (PH) && s_ >= 2) PL_COMBINE(((PH) + 2) & 3, s_ - 2)              \
    MAT_CORE(XS)                                                              \
    if (s_ < S_ - 2) {                                                        \
      (XS) = *(const float2*)(xgrp + ((PH) + 2) * I_);                        \
    }                                                                         \
    uP = hn * (CPH);                                                          \
    float h0n;                                                                \
    if (s_ == 0)            { hstartR = hn; h0n = 0.0f; }                     \
    else if (s_ == S_ - 2)  { h0n = fast_tanh(hn + hstartR); }                \
    else if (rd == 1)       { h0n = fast_tanh(hn + h0R); }                    \
    else if (cnt == 0)      { h0n = fast_tanh(hn + htR); htR = hn; }          \
    else                    { h0n = fast_tanh(hn); }                          \
    h0R = h0n;                                                                \
    if (wmask) h0_lds[((PH) + 1) & 1][hwoff] = h0n;                           \
    cnt = (cnt + 1 == rd) ? 0 : cnt + 1;                                      \
    sync_lds();                                                               \
  }

// LEAN4: rd==4 specialization, g in [1,254]. s%4 == PH%4 is COMPILE-TIME
// (8-wide unroll): no cnt bookkeeping, no residual cndmasks.
#define STEP_LEAN4(g, PH, XS, CPH)                                            \
  {                                                                           \
    const float* hb = &h0_lds[(PH) & 1][0];                                   \
    float4 hvA = *(const float4*)(hb + rdoff);                                \
    float4 hvB = *(const float4*)(hb + rdoff + 4);                            \
    UP_REDUCE(((PH) + 3) & 3)                                                 \
    if (w == (PH)) PL_COMBINE(((PH) + 2) & 3, (g) * 8 + (PH) - 2)             \
    MAT_CORE(XS)                                                              \
    (XS) = *(const float2*)(xgrp + ((PH) + 2) * I_);                          \
    uP = hn * (CPH);                                                          \
    float h0n;                                                                \
    if (((PH) & 3) == 0) { h0n = fast_tanh(hn + htR); htR = hn; }             \
    else                 { h0n = fast_tanh(hn); }                             \
    if (wmask) h0_lds[((PH) + 1) & 1][hwoff] = h0n;                           \
    sync_lds();                                                               \
  }

// Generic LEAN step (any rd): branchless residual, runtime cnt.
#define STEP_LEAN(g, PH, XS, CPH)                                             \
  {                                                                           \
    const float* hb = &h0_lds[(PH) & 1][0];                                   \
    float4 hvA = *(const float4*)(hb + rdoff);                                \
    float4 hvB = *(const float4*)(hb + rdoff + 4);                            \
    UP_REDUCE(((PH) + 3) & 3)                                                 \
    if (w == (PH)) PL_COMBINE(((PH) + 2) & 3, (g) * 8 + (PH) - 2)             \
    MAT_CORE(XS)                                                              \
    (XS) = *(const float2*)(xgrp + ((PH) + 2) * I_);                          \
    uP = hn * (CPH);                                                          \
    const bool c0 = (cnt == 0);                                               \
    float resid = rd1 ? h0R : (c0 ? htR : 0.0f);                              \
    float h0n = fast_tanh(hn + resid);                                        \
    htR = (htup && c0) ? hn : htR;                                            \
    h0R = h0n;                                                                \
    if (wmask) h0_lds[((PH) + 1) & 1][hwoff] = h0n;                           \
    cnt = (cnt + 1 == rd) ? 0 : cnt + 1;                                      \
    sync_lds();                                                               \
  }

// 512 threads = 8 waves per batch, 1 batch per block, 256 blocks = all CUs.
// Model (rounds 0-6, refit): wall ~= LDS-pipe drain (reads x ~12cy/b128)
// overlapped with VALU issue + serial chain tail. r6: 32 reads = 384cy pipe
// >= 355cy VALU -> LDS pipe binding. This round: 4h x 8k lane tiling halves
// reads (32 -> 16/CU-step) at ~ +13 VALU for the pure pre-stage; 48B chunk
// pitch keeps reads 2-way-conflict-free (free per m136).
__global__ __launch_bounds__(512)
__attribute__((amdgpu_waves_per_eu(2, 2)))
void rnn_kernel(
    const float* __restrict__ x, const float* __restrict__ Wi,
    const float* __restrict__ bi, const float* __restrict__ Wh,
    const float* __restrict__ bh, const float* __restrict__ Wa,
    const float* __restrict__ Wd, const int* __restrict__ rdp,
    float2* __restrict__ part)
{
    const int b = blockIdx.x;
    const int t = threadIdx.x;
    const int w = t >> 6;           // wave id 0..7
    const int l = t & 63;
    // k-group bits b0..b3; h-group bits b4,b5; role = b0+2*b1 (final h);
    // dup bits for hn: b2,b3 (hn independent of them after the tree)
    const int  kg4   = l & 15;                       // 16 k-groups x 8 k
    const int  hg2   = (l >> 4) & 3;                 // 4 h-groups x 4 h
    const int  hbase = 16 * w + 4 * hg2;
    const int  hf    = hbase + (l & 3);              // this lane's final h
    const bool kb0   = (l & 1);
    const bool kb1   = (l >> 1) & 1;
    const bool wmask = ((l & 0xC) == 0);             // 16 writer lanes
    const int  rdoff = kg4 * CHP;                    // h-read float offset
    const int  hwoff = (hf >> 3) * CHP + (hf & 7);   // h-write float offset

    __shared__ __align__(16) float h0_lds[2][16 * CHP];
    __shared__ __align__(8)  float2 pl_lds[4][32];  // ring x (8 waves x 4 grp)

    const int rd = rdp[0];
    const bool rd1  = (rd == 1);
    const bool htup = !rd1;
    if (t < 16 * CHP) h0_lds[0][t] = 0.0f;

    // Wh: lane's 8 k (k = 8*kg4 + c) x 4 h (hbase..hbase+4), packed pairs
    v2f W01[8], W23[8];
#pragma unroll
    for (int c = 0; c < 8; ++c) {
        int k = 8 * kg4 + c;
        float4 q = *(const float4*)(Wh + (size_t)k * H_ + hbase);
        W01[c] = mk2(q.x, q.y);
        W23[c] = mk2(q.z, q.w);
    }
    // Wi: lane's i-chunk {2kg4, 2kg4+1} x 4 h, packed pairs (rides k-tree)
    const int i0 = 2 * kg4;
    v2f WiF01[2], WiF23[2];
#pragma unroll
    for (int j = 0; j < 2; ++j) {
        float2 a = *(const float2*)(Wi + (size_t)(i0 + j) * H_ + hbase);
        float2 c = *(const float2*)(Wi + (size_t)(i0 + j) * H_ + hbase + 2);
        WiF01[j] = mk2(a.x, a.y);
        WiF23[j] = mk2(c.x, c.y);
    }
    // bias folded into acc init, gated to k-group 0 (enters the tree once)
    const bool k0g = (kg4 == 0);
    const v2f bias01 = k0g ? mk2(bi[hbase] + bh[hbase],
                                 bi[hbase + 1] + bh[hbase + 1]) : mk2(0.f, 0.f);
    const v2f bias23 = k0g ? mk2(bi[hbase + 2] + bh[hbase + 2],
                                 bi[hbase + 3] + bh[hbase + 3]) : mk2(0.f, 0.f);

    // Per-phase score/proj coefficient: class bit b2 selects pv (Wa) or qv
    // (Wd column for this b, phase s&7). Class-preserving reduce -> each h
    // counted exactly once per class, no duplication scale.
    const bool clsq = (l >> 2) & 1;   // b2: 0 = pv lane, 1 = qv lane
    const float waC = Wa[hf];
    float cph[8];
#pragma unroll
    for (int K = 0; K < 8; ++K)
        cph[K] = clsq ? Wd[(K << 15) + (b << 7) + hf] : waC;

    // x: each lane needs only its i-chunk (float2 at offset 2*kg4)
    const float* xgrp = x + (size_t)b * (S_ * I_) + i0;
    float2 xS0 = *(const float2*)xgrp;          // even-s slot
    float2 xS1 = *(const float2*)(xgrp + I_);   // odd-s slot

    sync_lds();

    float htR = 0.f, hstartR = 0.f, h0R = 0.f;
    float uP = 0.f;   // previous step's (hn * coef), reduced next step
    int cnt = 0;      // s % rd, incremental

    // g = 0 peeled (covers s==0 special + warm-up guards)
    {
        STEP_FULL(0, 0, xS0, cph[0])
        STEP_FULL(0, 1, xS1, cph[1])
        STEP_FULL(0, 2, xS0, cph[2])
        STEP_FULL(0, 3, xS1, cph[3])
        STEP_FULL(0, 4, xS0, cph[4])
        STEP_FULL(0, 5, xS1, cph[5])
        STEP_FULL(0, 6, xS0, cph[6])
        STEP_FULL(0, 7, xS1, cph[7])
        xgrp += 8 * I_;
    }
    if (rd == 4) {
        // hot loop, rd==4 (the bench value): cnt == PH%4 compile-time
        for (int g = 1; g < 255; ++g) {
            STEP_LEAN4(g, 0, xS0, cph[0])
            STEP_LEAN4(g, 1, xS1, cph[1])
            STEP_LEAN4(g, 2, xS0, cph[2])
            STEP_LEAN4(g, 3, xS1, cph[3])
            STEP_LEAN4(g, 4, xS0, cph[4])
            STEP_LEAN4(g, 5, xS1, cph[5])
            STEP_LEAN4(g, 6, xS0, cph[6])
            STEP_LEAN4(g, 7, xS1, cph[7])
            xgrp += 8 * I_;
        }
        cnt = 0;   // 2040 % 4 == 0, for the peeled tail
    } else {
        // generic hot loop (any rd, incl. rd==1)
        for (int g = 1; g < 255; ++g) {
            STEP_LEAN(g, 0, xS0, cph[0])
            STEP_LEAN(g, 1, xS1, cph[1])
            STEP_LEAN(g, 2, xS0, cph[2])
            STEP_LEAN(g, 3, xS1, cph[3])
            STEP_LEAN(g, 4, xS0, cph[4])
            STEP_LEAN(g, 5, xS1, cph[5])
            STEP_LEAN(g, 6, xS0, cph[6])
            STEP_LEAN(g, 7, xS1, cph[7])
            xgrp += 8 * I_;
        }
    }
    // g = 255 peeled (covers s==S_-2 special + refill clamp)
    {
        STEP_FULL(255, 0, xS0, cph[0])
        STEP_FULL(255, 1, xS1, cph[1])
        STEP_FULL(255, 2, xS0, cph[2])
        STEP_FULL(255, 3, xS1, cph[3])
        STEP_FULL(255, 4, xS0, cph[4])
        STEP_FULL(255, 5, xS1, cph[5])
        STEP_FULL(255, 6, xS0, cph[6])
        STEP_FULL(255, 7, xS1, cph[7])
    }

    // epilogue: reduce s = S-1's partial into ring 3 ((S_-1)&3), then
    // combine rings 2 (s = S-2, written at top of step S-1) and 3.
    UP_REDUCE(3)
    sync_lds();
    if (w == 0) PL_COMBINE(2, S_ - 2)
    if (w == 1) PL_COMBINE(3, S_ - 1)
}

// out[r] = bd + sum_{f in chunk r} softmax(score)_f * d_f, chunk = 2048 flat
// (s,b) pairs with s in [8r,8r+8). ba is softmax-invariant -> omitted.
__global__ __launch_bounds__(256) void attn_kernel(
    const float2* __restrict__ part, const float* __restrict__ bd,
    float* __restrict__ out)
{
    const int r = blockIdx.x;
    const int t = threadIdx.x;
    float sc[8], dv[8];
    float mx = -1e30f;
#pragma unroll
    for (int u = 0; u < 8; ++u) {
        int f = (r << 11) + (u << 8) + t;
        float2 a = part[f];
        sc[u] = a.x;
        dv[u] = a.y;
        mx = fmaxf(mx, sc[u]);
    }
    __shared__ float redm[4], redz[4], redw[4];
#pragma unroll
    for (int off = 32; off > 0; off >>= 1) mx = fmaxf(mx, __shfl_xor(mx, off, 64));
    if ((t & 63) == 0) redm[t >> 6] = mx;
    __syncthreads();
    mx = fmaxf(fmaxf(redm[0], redm[1]), fmaxf(redm[2], redm[3]));
    float z = 0.f, wv = 0.f;
#pragma unroll
    for (int u = 0; u < 8; ++u) {
        float e = __expf(sc[u] - mx);
        z += e;
        wv += e * dv[u];
    }
#pragma unroll
    for (int off = 32; off > 0; off >>= 1) {
        z += __shfl_xor(z, off, 64);
        wv += __shfl_xor(wv, off, 64);
    }
    if ((t & 63) == 0) { redz[t >> 6] = z; redw[t >> 6] = wv; }
    __syncthreads();
    if (t == 0) {
        float Z = redz[0] + redz[1] + redz[2] + redz[3];
        float W = redw[0] + redw[1] + redw[2] + redw[3];
        out[r] = bd[0] + W / Z;
    }
}

extern "C" void kernel_launch(void* const* d_in, const int* in_sizes, int n_in,
                              void* d_out, int out_size, void* d_ws, size_t ws_size,
                              hipStream_t stream) {
    const float* x  = (const float*)d_in[0];
    const float* Wi = (const float*)d_in[1];
    const float* bi = (const float*)d_in[2];
    const float* Wh = (const float*)d_in[3];
    const float* bh = (const float*)d_in[4];
    const float* Wa = (const float*)d_in[5];
    // d_in[6] = ba: constant shift inside each softmax chunk -> no effect.
    const float* Wd = (const float*)d_in[7];
    const float* bd = (const float*)d_in[8];
    const int*  rdp = (const int*)d_in[9];

    // Workspace: one (S*B) float2 array of combined {score, d} (4 MiB)
    float2* part = (float2*)d_ws;

    rnn_kernel<<<B_, 512, 0, stream>>>(x, Wi, bi, Wh, bh, Wa, Wd, rdp, part);
    attn_kernel<<<B_, 256, 0, stream>>>(part, bd, (float*)d_out);
}